// Round 5
// baseline (292.570 us; speedup 1.0000x reference)
//
#include <hip/hip_runtime.h>
#include <math.h>

#define H 512
#define W 512
#define NC 64
#define NTOT (NC * H * W)
#define RAD 4
#define TILE 32
#define COLLEN 49        // float4 slots per column: 48 rows + 1 pad (49%8=1 -> bank spread)
#define PL (10 * COLLEN) // plane stride in float4

typedef float vfloat4 __attribute__((ext_vector_type(4)));  // native vec for nt-store

__device__ __forceinline__ float4 f4add(float4 a, float4 b) {
    return make_float4(a.x + b.x, a.y + b.y, a.z + b.z, a.w + b.w);
}
__device__ __forceinline__ float4 f4sub(float4 a, float4 b) {
    return make_float4(a.x - b.x, a.y - b.y, a.z - b.z, a.w - b.w);
}
__device__ __forceinline__ float4 f4mul(float4 a, float4 b) {
    return make_float4(a.x * b.x, a.y * b.y, a.z * b.z, a.w * b.w);
}
__device__ __forceinline__ float4 f4scale(float4 a, float s) {
    return make_float4(a.x * s, a.y * s, a.z * s, a.w * s);
}
__device__ __forceinline__ float4 f4adds(float4 a, float s) {
    return make_float4(a.x + s, a.y + s, a.z + s, a.w + s);
}
__device__ __forceinline__ float4 f4absv(float4 a) {
    return make_float4(fabsf(a.x), fabsf(a.y), fabsf(a.z), fabsf(a.w));
}
__device__ __forceinline__ float4 f4rcp(float4 a) {
    return make_float4(__builtin_amdgcn_rcpf(a.x), __builtin_amdgcn_rcpf(a.y),
                       __builtin_amdgcn_rcpf(a.z), __builtin_amdgcn_rcpf(a.w));
}

// h-sum of 9-window over 16 consecutive values -> 8 outputs (cols 4..11 of the 16)
__device__ __forceinline__ void hsum9x2(const float* v, float4* o0, float4* o1) {
    float h = v[0] + v[1] + v[2] + v[3] + v[4] + v[5] + v[6] + v[7] + v[8];
    float r[8];
    r[0] = h;
#pragma unroll
    for (int m = 1; m < 8; ++m) {
        h += v[m + 8] - v[m - 1];
        r[m] = h;
    }
    *o0 = make_float4(r[0], r[1], r[2], r[3]);
    *o1 = make_float4(r[4], r[5], r[6], r[7]);
}

// ---------- sum of |a|+1e-12, atomic-free two-stage ----------
__global__ __launch_bounds__(256) void sum_abs_stage1(const float* __restrict__ a,
                                                      double* __restrict__ ws) {
    __shared__ double red[4];
    const float4* a4 = (const float4*)a;
    int tid = threadIdx.x;
    double s = 0.0;
    for (int i = blockIdx.x * 256 + tid; i < NTOT / 4; i += 1024 * 256) {
        float4 v = a4[i];
        s += (double)fabsf(v.x) + (double)fabsf(v.y) + (double)fabsf(v.z) + (double)fabsf(v.w);
    }
    for (int off = 32; off; off >>= 1) s += __shfl_down(s, off);
    if ((tid & 63) == 0) red[tid >> 6] = s;
    __syncthreads();
    if (tid == 0) ws[1 + blockIdx.x] = red[0] + red[1] + red[2] + red[3];
}

__global__ __launch_bounds__(256) void sum_abs_stage2(double* __restrict__ ws) {
    __shared__ double red[4];
    int tid = threadIdx.x;
    double s = 0.0;
#pragma unroll
    for (int k = 0; k < 4; ++k) s += ws[1 + tid + k * 256];
    for (int off = 32; off; off >>= 1) s += __shfl_down(s, off);
    if ((tid & 63) == 0) red[tid >> 6] = s;
    __syncthreads();
    if (tid == 0) ws[0] = red[0] + red[1] + red[2] + red[3] + (double)NTOT * 1e-12;
}

// ---------- fused guided filter, 32x32 tile ----------
// LDS: 6 planes, column-major float4: P[(plane*10 + mq)*COLLEN + row]
// planes: 0:a 1:ax 2:ay 3:ax^2 4:ax*ay 5:a*ax ; planes 0/1 reused for A/b,
// planes 2/3 reused for boxed A/b (P4 out-of-place).
// Barriers: P1 | C-compute | C-write | P4 | P5  (4 syncs, was 6).
__global__ __launch_bounds__(256, 3) void fgf_kernel(const float* __restrict__ Xg,
                                                     const float* __restrict__ Yg,
                                                     const float* __restrict__ Ag,
                                                     const double* __restrict__ Ssum,
                                                     float* __restrict__ outg) {
    __shared__ float4 P[6 * PL];   // 47040 B -> 3 blocks/CU (LDS-capped)

    const int tid = threadIdx.x;
    const int ch = blockIdx.z;
    const int tr = blockIdx.y, tc = blockIdx.x;
    const int gr0 = tr * TILE - 8, gc0 = tc * TILE - 8;
    const size_t chOff = (size_t)ch * H * W;
    const float* Xc = Xg + chOff;
    const float* Yc = Yg + chOff;
    const float* Ac = Ag + chOff;
    const float invS = (float)(1.0 / Ssum[0]);
    // Block never touches an image edge: whole 48x48 input window in-bounds and
    // every box window is the full 9x9 (N = 81). Uniform SGPR branch, no divergence.
    const bool interior = (tr >= 1) && (tr <= 14) && (tc >= 1) && (tc <= 14);

    // ---- Phase 1: 240 tasks = 48 rows x 5 col-pairs. Each task loads a 16-col
    // strip (4 float4 per array), h-sums the 9-window -> 8 outputs (quads 2mp, 2mp+1).
    if (tid < 240) {
        const int i = tid / 5, mp = tid % 5;
        const int gr = gr0 + i;
        const int gcb = gc0 + 8 * mp;
        const float* rowx = Xc + (size_t)gr * W;
        const float* rowy = Yc + (size_t)gr * W;
        const float* rowa = Ac + (size_t)gr * W;
        float xr[16], yr[16], ar[16];
        if (interior) {
            // unguarded: 12 clustered global_load_dwordx4, one vmcnt batch
#pragma unroll
            for (int k = 0; k < 4; ++k) {
                const int gc = gcb + 4 * k;
                float4 xv = *(const float4*)(rowx + gc);
                float4 yv = *(const float4*)(rowy + gc);
                float4 av = *(const float4*)(rowa + gc);
                xr[4 * k] = xv.x; xr[4 * k + 1] = xv.y; xr[4 * k + 2] = xv.z; xr[4 * k + 3] = xv.w;
                yr[4 * k] = yv.x; yr[4 * k + 1] = yv.y; yr[4 * k + 2] = yv.z; yr[4 * k + 3] = yv.w;
                ar[4 * k] = av.x; ar[4 * k + 1] = av.y; ar[4 * k + 2] = av.z; ar[4 * k + 3] = av.w;
            }
        } else {
            const bool rok = (gr >= 0) && (gr < H);
#pragma unroll
            for (int k = 0; k < 4; ++k) {
                const int gc = gcb + 4 * k;
                float4 xv = make_float4(0.f, 0.f, 0.f, 0.f), yv = xv, av = xv;
                if (rok && gc >= 0 && gc < W) {
                    xv = *(const float4*)(rowx + gc);
                    yv = *(const float4*)(rowy + gc);
                    av = *(const float4*)(rowa + gc);
                }
                xr[4 * k] = xv.x; xr[4 * k + 1] = xv.y; xr[4 * k + 2] = xv.z; xr[4 * k + 3] = xv.w;
                yr[4 * k] = yv.x; yr[4 * k + 1] = yv.y; yr[4 * k + 2] = yv.z; yr[4 * k + 3] = yv.w;
                ar[4 * k] = av.x; ar[4 * k + 1] = av.y; ar[4 * k + 2] = av.z; ar[4 * k + 3] = av.w;
            }
        }
        // per-element +1e-12 dropped (f32: |a|+1e-12 == |a| except |a|<8.4e-6;
        // sum perturbation ~1e-12 << tol). Global-sum epsilon kept in stage2.
        float a_[16], ax_[16], ay_[16];
#pragma unroll
        for (int j = 0; j < 16; ++j) {
            float aa = fabsf(ar[j]);
            a_[j] = aa; ax_[j] = aa * xr[j]; ay_[j] = aa * yr[j];
        }
        float4* base = P + (2 * mp) * COLLEN + i;   // quad 2mp; quad 2mp+1 at +COLLEN
        float4 q0, q1;
        hsum9x2(a_, &q0, &q1);
        base[0 * PL] = q0; base[0 * PL + COLLEN] = q1;
        hsum9x2(ax_, &q0, &q1);
        base[1 * PL] = q0; base[1 * PL + COLLEN] = q1;
        hsum9x2(ay_, &q0, &q1);
        base[2 * PL] = q0; base[2 * PL + COLLEN] = q1;
        float t[16];
#pragma unroll
        for (int j = 0; j < 16; ++j) t[j] = ax_[j] * ax_[j];
        hsum9x2(t, &q0, &q1);
        base[3 * PL] = q0; base[3 * PL + COLLEN] = q1;
#pragma unroll
        for (int j = 0; j < 16; ++j) t[j] = ax_[j] * ay_[j];
        hsum9x2(t, &q0, &q1);
        base[4 * PL] = q0; base[4 * PL + COLLEN] = q1;
#pragma unroll
        for (int j = 0; j < 16; ++j) t[j] = a_[j] * ax_[j];
        hsum9x2(t, &q0, &q1);
        base[5 * PL] = q0; base[5 * PL + COLLEN] = q1;
    }
    __syncthreads();

    // ---- Phase C: fused vertical 9-box + solve. 100 threads = 10 mq x 10 segs(4 rows).
    // Each thread streams the 6 planes' 12-row windows through regs (plane order
    // caps live set), v-boxes 4 rows each, solves A,b directly. The six box planes
    // are never written back. A,b writes (in-place, planes 0/1) deferred past barrier.
    {
        float4 Av[4], Bv[4], msk[4];
        const int mqC = tid % 10;
        const int r0C = (tid / 10) * 4;
        if (tid < 100) {
            const float4* colbase = P + mqC * COLLEN + r0C;
            float4 wv[12];
            float4 s6v[4], s4v[4], dp[4], np[4], u[4];

#define VBOX(PLN, OUT)                                                        \
            {                                                                 \
                const float4* c_ = colbase + (PLN) * PL;                      \
                _Pragma("unroll") for (int k = 0; k < 12; ++k) wv[k] = c_[k]; \
                float4 acc = wv[0];                                           \
                _Pragma("unroll") for (int k = 1; k < 9; ++k) acc = f4add(acc, wv[k]); \
                OUT[0] = acc;                                                 \
                _Pragma("unroll") for (int m = 1; m < 4; ++m) {               \
                    acc = f4add(acc, f4sub(wv[m + 8], wv[m - 1]));            \
                    OUT[m] = acc;                                             \
                }                                                             \
            }

            // s3 = box(a*ax): temporary home in dp, combined immediately
            float4 s3v[4];
            VBOX(5, s3v)
            VBOX(1, s6v)
#pragma unroll
            for (int m = 0; m < 4; ++m) dp[m] = f4scale(f4mul(s3v[m], s6v[m]), invS);
            VBOX(2, s4v)
#pragma unroll
            for (int m = 0; m < 4; ++m) np[m] = f4scale(f4mul(s3v[m], s4v[m]), invS); // s3v dead
            VBOX(4, u)    // s2
#pragma unroll
            for (int m = 0; m < 4; ++m) np[m] = f4sub(u[m], np[m]);   // num
            VBOX(3, u)    // s5
            if (interior) {
#pragma unroll
                for (int m = 0; m < 4; ++m) {
                    float4 den = f4adds(f4absv(f4sub(u[m], dp[m])), 8.1e-7f);
                    Av[m] = f4mul(np[m], f4rcp(den));
                }
            } else {
#pragma unroll
                for (int m = 0; m < 4; ++m) {
                    const int gr = gr0 + RAD + r0C + m;
                    const bool rokm = (gr >= 0) && (gr < H);
                    const float fy = (float)(min(H - 1, gr + RAD) - max(0, gr - RAD) + 1);
                    float4 A4 = make_float4(0.f, 0.f, 0.f, 0.f), M4 = A4;
                    if (rokm) {
#define CSOLVE(cc, off)                                                       \
                        {                                                     \
                            const int gc = gc0 + RAD + 4 * mqC + off;         \
                            if (gc >= 0 && gc < W) {                          \
                                float cx = (float)(min(W - 1, gc + RAD) - max(0, gc - RAD) + 1); \
                                float den = fabsf(u[m].cc - dp[m].cc) + 1e-8f * (fy * cx); \
                                A4.cc = np[m].cc * __builtin_amdgcn_rcpf(den); \
                                M4.cc = 1.f;                                  \
                            }                                                 \
                        }
                        CSOLVE(x, 0) CSOLVE(y, 1) CSOLVE(z, 2) CSOLVE(w, 3)
#undef CSOLVE
                    }
                    Av[m] = A4; msk[m] = M4;
                }
            }
            VBOX(0, u)    // s1
            if (interior) {
#pragma unroll
                for (int m = 0; m < 4; ++m)
                    Bv[m] = f4mul(f4sub(s4v[m], f4mul(Av[m], s6v[m])), f4rcp(u[m]));
            } else {
#pragma unroll
                for (int m = 0; m < 4; ++m) {
                    float4 B4 = f4mul(f4sub(s4v[m], f4mul(Av[m], s6v[m])), f4rcp(u[m]));
                    // select (not multiply): s1 may be 0 at invalid cols -> inf/NaN
                    Bv[m].x = (msk[m].x != 0.f) ? B4.x : 0.f;
                    Bv[m].y = (msk[m].y != 0.f) ? B4.y : 0.f;
                    Bv[m].z = (msk[m].z != 0.f) ? B4.z : 0.f;
                    Bv[m].w = (msk[m].w != 0.f) ? B4.w : 0.f;
                }
            }
#undef VBOX
        }
        __syncthreads();
        if (tid < 100) {
            float4* c0 = P + mqC * COLLEN + r0C;
#pragma unroll
            for (int m = 0; m < 4; ++m) {
                c0[0 * PL + m] = Av[m];
                c0[1 * PL + m] = Bv[m];
            }
        }
        __syncthreads();
    }

    // ---- Phase 4: vertical 9-box on A/b, OUT-OF-PLACE into planes 2/3 (dead after C).
    // 160 threads = 8 segs x {A,b} x 10 mq. No preload, no internal barrier.
    {
        const int rem = tid % 20;
        const int pq4 = (rem / 10) * 10 + (rem % 10);   // plane(0/1)*10 + mq
        const int r0 = (tid / 20) * 4;
        if (tid < 160) {
            const float4* col = P + pq4 * COLLEN + r0;
            float4* dst = P + (pq4 + 20) * COLLEN + r0;  // +2 planes
            float4 u[12];
#pragma unroll
            for (int k = 0; k < 12; ++k) u[k] = col[k];
            float4 s = u[0];
#pragma unroll
            for (int k = 1; k < 9; ++k) s = f4add(s, u[k]);
            dst[0] = s;
#pragma unroll
            for (int m = 1; m < 4; ++m) {
                s = f4add(s, f4sub(u[m + 8], u[m - 1]));
                dst[m] = s;
            }
        }
        __syncthreads();
    }

    // ---- Phase 5: horizontal 9-box on boxed A/b (planes 2/3) + final affine;
    // 256 threads, 1 out-quad each ----
    {
        const int orow = tid >> 3, oq = tid & 7;
        const float4* cA = P + 2 * PL + oq * COLLEN + orow;
        const float4* cB = cA + 1 * PL;
        float4 a0 = cA[0], a1 = cA[COLLEN], a2 = cA[2 * COLLEN];
        float4 b0 = cB[0], b1 = cB[COLLEN], b2 = cB[2 * COLLEN];
        float hA0 = a0.x + a0.y + a0.z + a0.w + a1.x + a1.y + a1.z + a1.w + a2.x;
        float hA1 = hA0 - a0.x + a2.y;
        float hA2 = hA1 - a0.y + a2.z;
        float hA3 = hA2 - a0.z + a2.w;
        float hB0 = b0.x + b0.y + b0.z + b0.w + b1.x + b1.y + b1.z + b1.w + b2.x;
        float hB1 = hB0 - b0.x + b2.y;
        float hB2 = hB1 - b0.y + b2.z;
        float hB3 = hB2 - b0.z + b2.w;
        const int gr = tr * TILE + orow, gc = tc * TILE + 4 * oq;
        float4 xv = *(const float4*)(Xc + (size_t)gr * W + gc);
        vfloat4 o;
        if (interior) {
            const float inv81 = 1.0f / 81.0f;   // exact constant, beats v_rcp chain
            o.x = (hA0 * xv.x + hB0) * inv81;
            o.y = (hA1 * xv.y + hB1) * inv81;
            o.z = (hA2 * xv.z + hB2) * inv81;
            o.w = (hA3 * xv.w + hB3) * inv81;
        } else {
            const float fy = (float)(min(H - 1, gr + RAD) - max(0, gr - RAD) + 1);
#define FIN(cc, hA, hB, off)                                                        \
            {                                                                       \
                float cx = (float)(min(W - 1, gc + off + RAD) - max(0, gc + off - RAD) + 1); \
                o.cc = (hA * xv.cc + hB) * __builtin_amdgcn_rcpf(fy * cx);          \
            }
            FIN(x, hA0, hB0, 0) FIN(y, hA1, hB1, 1) FIN(z, hA2, hB2, 2) FIN(w, hA3, hB3, 3)
#undef FIN
        }
        __builtin_nontemporal_store(o, (vfloat4*)(outg + chOff + (size_t)gr * W + gc));
    }
}

extern "C" void kernel_launch(void* const* d_in, const int* in_sizes, int n_in,
                              void* d_out, int out_size, void* d_ws, size_t ws_size,
                              hipStream_t stream) {
    const float* lr_x = (const float*)d_in[0];
    const float* lr_y = (const float*)d_in[1];
    const float* l_a  = (const float*)d_in[2];
    float* out = (float*)d_out;
    double* dws = (double*)d_ws;

    sum_abs_stage1<<<1024, 256, 0, stream>>>(l_a, dws);
    sum_abs_stage2<<<1, 256, 0, stream>>>(dws);

    dim3 grid(W / TILE, H / TILE, NC);
    fgf_kernel<<<grid, 256, 0, stream>>>(lr_x, lr_y, l_a, dws, out);
}

// Round 6
// 284.282 us; speedup vs baseline: 1.0292x; 1.0292x over previous
//
#include <hip/hip_runtime.h>
#include <math.h>

#define H 512
#define W 512
#define NC 64
#define NTOT (NC * H * W)
#define RAD 4
#define TILE 32
#define COLLEN 49        // float4 slots per column: 48 rows + 1 pad (49%8=1 -> bank spread)
#define PL (10 * COLLEN) // plane stride in float4

typedef float vfloat4 __attribute__((ext_vector_type(4)));  // native vec for nt-store

__device__ __forceinline__ float4 f4add(float4 a, float4 b) {
    return make_float4(a.x + b.x, a.y + b.y, a.z + b.z, a.w + b.w);
}
__device__ __forceinline__ float4 f4sub(float4 a, float4 b) {
    return make_float4(a.x - b.x, a.y - b.y, a.z - b.z, a.w - b.w);
}

// h-sum of 9-window over 16 consecutive values -> 8 outputs (cols 4..11 of the 16)
__device__ __forceinline__ void hsum9x2(const float* v, float4* o0, float4* o1) {
    float h = v[0] + v[1] + v[2] + v[3] + v[4] + v[5] + v[6] + v[7] + v[8];
    float r[8];
    r[0] = h;
#pragma unroll
    for (int m = 1; m < 8; ++m) {
        h += v[m + 8] - v[m - 1];
        r[m] = h;
    }
    *o0 = make_float4(r[0], r[1], r[2], r[3]);
    *o1 = make_float4(r[4], r[5], r[6], r[7]);
}

// ---------- sum of |a|+1e-12, atomic-free two-stage ----------
__global__ __launch_bounds__(256) void sum_abs_stage1(const float* __restrict__ a,
                                                      double* __restrict__ ws) {
    __shared__ double red[4];
    const float4* a4 = (const float4*)a;
    int tid = threadIdx.x;
    double s = 0.0;
    for (int i = blockIdx.x * 256 + tid; i < NTOT / 4; i += 1024 * 256) {
        float4 v = a4[i];
        s += (double)fabsf(v.x) + (double)fabsf(v.y) + (double)fabsf(v.z) + (double)fabsf(v.w);
    }
    for (int off = 32; off; off >>= 1) s += __shfl_down(s, off);
    if ((tid & 63) == 0) red[tid >> 6] = s;
    __syncthreads();
    if (tid == 0) ws[1 + blockIdx.x] = red[0] + red[1] + red[2] + red[3];
}

__global__ __launch_bounds__(256) void sum_abs_stage2(double* __restrict__ ws) {
    __shared__ double red[4];
    int tid = threadIdx.x;
    double s = 0.0;
#pragma unroll
    for (int k = 0; k < 4; ++k) s += ws[1 + tid + k * 256];
    for (int off = 32; off; off >>= 1) s += __shfl_down(s, off);
    if ((tid & 63) == 0) red[tid >> 6] = s;
    __syncthreads();
    if (tid == 0) ws[0] = red[0] + red[1] + red[2] + red[3] + (double)NTOT * 1e-12;
}

// ---------- fused guided filter, 32x32 tile ----------
// LDS: 6 planes, column-major float4: P[(plane*10 + mq)*COLLEN + row]
// planes: 0:a 1:ax 2:ay 3:ax^2 4:ax*ay 5:a*ax ; planes 0/1 reused for A/b,
// planes 2/3 reused for boxed A/b (P4 out-of-place; 2..5 dead after P3).
// Barriers: 5 (was 6) — P4's internal preload barrier removed.
__global__ __launch_bounds__(256) void fgf_kernel(const float* __restrict__ Xg,
                                                  const float* __restrict__ Yg,
                                                  const float* __restrict__ Ag,
                                                  const double* __restrict__ Ssum,
                                                  float* __restrict__ outg) {
    __shared__ float4 P[6 * PL];   // 47040 B -> 3 blocks/CU

    const int tid = threadIdx.x;
    const int ch = blockIdx.z;
    const int tr = blockIdx.y, tc = blockIdx.x;
    const int gr0 = tr * TILE - 8, gc0 = tc * TILE - 8;
    const size_t chOff = (size_t)ch * H * W;
    const float* Xc = Xg + chOff;
    const float* Yc = Yg + chOff;
    const float* Ac = Ag + chOff;
    const float invS = (float)(1.0 / Ssum[0]);
    // Block never touches an image edge: whole 48x48 input window in-bounds and
    // every box window is the full 9x9 (N = 81). Uniform SGPR branch, no divergence.
    const bool interior = (tr >= 1) && (tr <= 14) && (tc >= 1) && (tc <= 14);

    // ---- Phase 1: 240 tasks = 48 rows x 5 col-pairs. Each task loads a 16-col
    // strip (4 float4 per array), h-sums the 9-window -> 8 outputs (quads 2mp, 2mp+1).
    if (tid < 240) {
        const int i = tid / 5, mp = tid % 5;
        const int gr = gr0 + i;
        const int gcb = gc0 + 8 * mp;
        const float* rowx = Xc + (size_t)gr * W;
        const float* rowy = Yc + (size_t)gr * W;
        const float* rowa = Ac + (size_t)gr * W;
        float xr[16], yr[16], ar[16];
        if (interior) {
            // unguarded: 12 clustered global_load_dwordx4, one vmcnt batch
#pragma unroll
            for (int k = 0; k < 4; ++k) {
                const int gc = gcb + 4 * k;
                float4 xv = *(const float4*)(rowx + gc);
                float4 yv = *(const float4*)(rowy + gc);
                float4 av = *(const float4*)(rowa + gc);
                xr[4 * k] = xv.x; xr[4 * k + 1] = xv.y; xr[4 * k + 2] = xv.z; xr[4 * k + 3] = xv.w;
                yr[4 * k] = yv.x; yr[4 * k + 1] = yv.y; yr[4 * k + 2] = yv.z; yr[4 * k + 3] = yv.w;
                ar[4 * k] = av.x; ar[4 * k + 1] = av.y; ar[4 * k + 2] = av.z; ar[4 * k + 3] = av.w;
            }
        } else {
            const bool rok = (gr >= 0) && (gr < H);
#pragma unroll
            for (int k = 0; k < 4; ++k) {
                const int gc = gcb + 4 * k;
                float4 xv = make_float4(0.f, 0.f, 0.f, 0.f), yv = xv, av = xv;
                if (rok && gc >= 0 && gc < W) {
                    xv = *(const float4*)(rowx + gc);
                    yv = *(const float4*)(rowy + gc);
                    av = *(const float4*)(rowa + gc);
                }
                xr[4 * k] = xv.x; xr[4 * k + 1] = xv.y; xr[4 * k + 2] = xv.z; xr[4 * k + 3] = xv.w;
                yr[4 * k] = yv.x; yr[4 * k + 1] = yv.y; yr[4 * k + 2] = yv.z; yr[4 * k + 3] = yv.w;
                ar[4 * k] = av.x; ar[4 * k + 1] = av.y; ar[4 * k + 2] = av.z; ar[4 * k + 3] = av.w;
            }
        }
        // per-element +1e-12 dropped (f32: |a|+1e-12 == |a| except |a|<8.4e-6;
        // sum perturbation ~1e-12 << tol). Global-sum epsilon kept in stage2.
        float a_[16], ax_[16], ay_[16];
#pragma unroll
        for (int j = 0; j < 16; ++j) {
            float aa = fabsf(ar[j]);
            a_[j] = aa; ax_[j] = aa * xr[j]; ay_[j] = aa * yr[j];
        }
        float4* base = P + (2 * mp) * COLLEN + i;   // quad 2mp; quad 2mp+1 at +COLLEN
        float4 q0, q1;
        hsum9x2(a_, &q0, &q1);
        base[0 * PL] = q0; base[0 * PL + COLLEN] = q1;
        hsum9x2(ax_, &q0, &q1);
        base[1 * PL] = q0; base[1 * PL + COLLEN] = q1;
        hsum9x2(ay_, &q0, &q1);
        base[2 * PL] = q0; base[2 * PL + COLLEN] = q1;
        float t[16];
#pragma unroll
        for (int j = 0; j < 16; ++j) t[j] = ax_[j] * ax_[j];
        hsum9x2(t, &q0, &q1);
        base[3 * PL] = q0; base[3 * PL + COLLEN] = q1;
#pragma unroll
        for (int j = 0; j < 16; ++j) t[j] = ax_[j] * ay_[j];
        hsum9x2(t, &q0, &q1);
        base[4 * PL] = q0; base[4 * PL + COLLEN] = q1;
#pragma unroll
        for (int j = 0; j < 16; ++j) t[j] = a_[j] * ax_[j];
        hsum9x2(t, &q0, &q1);
        base[5 * PL] = q0; base[5 * PL + COLLEN] = q1;
    }
    __syncthreads();

    // ---- Phase 2: vertical 9-box, in-place. 240 threads = 6 planes x 10 mq x 4 segs.
    // Whole 18-row input window preloaded to regs BEFORE barrier (halo race -> barrier).
    {
        const int pq2 = tid % 60;
        const int r0 = (tid / 60) * 10;
        float4* col = P + pq2 * COLLEN;
        float4 wv[18];
        if (tid < 240) {
#pragma unroll
            for (int k = 0; k < 18; ++k) wv[k] = col[r0 + k];
        }
        __syncthreads();
        if (tid < 240) {
            float4 s = wv[0];
#pragma unroll
            for (int k = 1; k < 9; ++k) s = f4add(s, wv[k]);
            col[r0] = s;
#pragma unroll
            for (int m = 1; m < 10; ++m) {
                s = f4add(s, f4sub(wv[m + 8], wv[m - 1]));
                col[r0 + m] = s;
            }
        }
        __syncthreads();
    }

    // ---- Phase 3: solve A,b per mid quad (40x40 -> 400 quads), in-place planes 0/1 ----
#pragma unroll
    for (int pass = 0; pass < 2; ++pass) {
        const int idx = tid + pass * 256;
        if (idx < 400) {
            const int mi = idx / 10, mq = idx % 10;
            float4* c0 = P + mq * COLLEN + mi;
            float4 s1 = c0[0 * PL];
            float4 s6 = c0[1 * PL];
            float4 s4 = c0[2 * PL];
            float4 s5 = c0[3 * PL];
            float4 s2 = c0[4 * PL];
            float4 s3 = c0[5 * PL];
            float4 A4 = make_float4(0.f, 0.f, 0.f, 0.f), B4 = A4;
            if (interior) {
                // full 9x9 windows: N = 81 -> eps term constant
#define SOLVEI(cc)                                                                  \
                {                                                                   \
                    float num = s2.cc - s3.cc * s4.cc * invS;                       \
                    float den = fabsf(s5.cc - s3.cc * s6.cc * invS) + 8.1e-7f;      \
                    float Av = num * __builtin_amdgcn_rcpf(den);                    \
                    A4.cc = Av;                                                     \
                    B4.cc = (s4.cc - Av * s6.cc) * __builtin_amdgcn_rcpf(s1.cc);    \
                }
                SOLVEI(x) SOLVEI(y) SOLVEI(z) SOLVEI(w)
#undef SOLVEI
            } else {
                const int gr = gr0 + RAD + mi, gc = gc0 + RAD + 4 * mq;
                if (gr >= 0 && gr < H && gc >= 0 && gc < W) {
                    const float fy = (float)(min(H - 1, gr + RAD) - max(0, gr - RAD) + 1);
#define SOLVE(cc, off)                                                              \
                    {                                                               \
                        float cx = (float)(min(W - 1, gc + off + RAD) - max(0, gc + off - RAD) + 1); \
                        float Nf = fy * cx;                                         \
                        float num = s2.cc - s3.cc * s4.cc * invS;                   \
                        float den = fabsf(s5.cc - s3.cc * s6.cc * invS) + 1e-8f * Nf; \
                        float Av = num * __builtin_amdgcn_rcpf(den);                \
                        A4.cc = Av;                                                 \
                        B4.cc = (s4.cc - Av * s6.cc) * __builtin_amdgcn_rcpf(s1.cc); \
                    }
                    SOLVE(x, 0) SOLVE(y, 1) SOLVE(z, 2) SOLVE(w, 3)
#undef SOLVE
                }
            }
            c0[0 * PL] = A4;
            c0[1 * PL] = B4;
        }
    }
    __syncthreads();

    // ---- P5's X-tile global load, hoisted ABOVE P4: its HBM/L2 latency hides
    // under P4's LDS work + barrier instead of sitting on the final critical path.
    float4 xv;
    {
        const int orow = tid >> 3, oq = tid & 7;
        xv = *(const float4*)(Xc + (size_t)(tr * TILE + orow) * W + (tc * TILE + 4 * oq));
    }

    // ---- Phase 4: vertical 9-box on A/b, OUT-OF-PLACE into planes 2/3 (dead
    // after P3). 160 threads = 8 segs x {A,b} x 10 mq. No preload barrier:
    // reads planes 0/1, writes planes 2/3 -> no RAW/WAR hazard.
    {
        const int pq4 = tid % 20;                        // plane(0/1)*10 + mq
        const int r0 = (tid / 20) * 4;
        if (tid < 160) {
            const float4* col = P + pq4 * COLLEN + r0;
            float4* dst = P + (pq4 + 20) * COLLEN + r0;  // planes 2/3
            float4 u[12];
#pragma unroll
            for (int k = 0; k < 12; ++k) u[k] = col[k];
            float4 s = u[0];
#pragma unroll
            for (int k = 1; k < 9; ++k) s = f4add(s, u[k]);
            dst[0] = s;
#pragma unroll
            for (int m = 1; m < 4; ++m) {
                s = f4add(s, f4sub(u[m + 8], u[m - 1]));
                dst[m] = s;
            }
        }
        __syncthreads();
    }

    // ---- Phase 5: horizontal 9-box on boxed A/b (planes 2/3) + final affine;
    // 256 threads, 1 out-quad each ----
    {
        const int orow = tid >> 3, oq = tid & 7;
        const float4* cA = P + 2 * PL + oq * COLLEN + orow;
        const float4* cB = cA + 1 * PL;
        float4 a0 = cA[0], a1 = cA[COLLEN], a2 = cA[2 * COLLEN];
        float4 b0 = cB[0], b1 = cB[COLLEN], b2 = cB[2 * COLLEN];
        float hA0 = a0.x + a0.y + a0.z + a0.w + a1.x + a1.y + a1.z + a1.w + a2.x;
        float hA1 = hA0 - a0.x + a2.y;
        float hA2 = hA1 - a0.y + a2.z;
        float hA3 = hA2 - a0.z + a2.w;
        float hB0 = b0.x + b0.y + b0.z + b0.w + b1.x + b1.y + b1.z + b1.w + b2.x;
        float hB1 = hB0 - b0.x + b2.y;
        float hB2 = hB1 - b0.y + b2.z;
        float hB3 = hB2 - b0.z + b2.w;
        const int gr = tr * TILE + orow, gc = tc * TILE + 4 * oq;
        vfloat4 o;
        if (interior) {
            const float inv81 = 1.0f / 81.0f;   // exact constant, beats v_rcp chain
            o.x = (hA0 * xv.x + hB0) * inv81;
            o.y = (hA1 * xv.y + hB1) * inv81;
            o.z = (hA2 * xv.z + hB2) * inv81;
            o.w = (hA3 * xv.w + hB3) * inv81;
        } else {
            const float fy = (float)(min(H - 1, gr + RAD) - max(0, gr - RAD) + 1);
#define FIN(cc, hA, hB, off)                                                        \
            {                                                                       \
                float cx = (float)(min(W - 1, gc + off + RAD) - max(0, gc + off - RAD) + 1); \
                o.cc = (hA * xv.cc + hB) * __builtin_amdgcn_rcpf(fy * cx);          \
            }
            FIN(x, hA0, hB0, 0) FIN(y, hA1, hB1, 1) FIN(z, hA2, hB2, 2) FIN(w, hA3, hB3, 3)
#undef FIN
        }
        __builtin_nontemporal_store(o, (vfloat4*)(outg + chOff + (size_t)gr * W + gc));
    }
}

extern "C" void kernel_launch(void* const* d_in, const int* in_sizes, int n_in,
                              void* d_out, int out_size, void* d_ws, size_t ws_size,
                              hipStream_t stream) {
    const float* lr_x = (const float*)d_in[0];
    const float* lr_y = (const float*)d_in[1];
    const float* l_a  = (const float*)d_in[2];
    float* out = (float*)d_out;
    double* dws = (double*)d_ws;

    sum_abs_stage1<<<1024, 256, 0, stream>>>(l_a, dws);
    sum_abs_stage2<<<1, 256, 0, stream>>>(dws);

    dim3 grid(W / TILE, H / TILE, NC);
    fgf_kernel<<<grid, 256, 0, stream>>>(lr_x, lr_y, l_a, dws, out);
}